// Round 1
// baseline (114.066 us; speedup 1.0000x reference)
//
#include <hip/hip_runtime.h>
#include <math.h>

#define BATCH 64
#define TLEN 2048
#define DIM 80
#define WIDTH 8               // dims per thread (R8: was 4; halves halo-load + row overhead)
#define DG (DIM / WIDTH)      // 10 groups per row
#define TT 4                  // t-rows per thread strip
#define TCHUNKS (TLEN / TT)   // 512
#define THREADS 128           // R8: 128-thread blocks -> NBLOCKS=2560 -> EXACTLY 10 wg/CU
                              // resident (20 waves/CU, 5/SIMD), zero tail rounds.
#define NSTRIPS (BATCH * TCHUNKS * DG)        // 327680 threads
#define NBLOCKS (NSTRIPS / THREADS)           // 2560

// Smooth-min: K=32; c = K*log2(e)
#define SMIN_C  46.166241308446828f
#define SMIN_RC 0.02166084939249829f   // 1/c

// LESSON (R3-R5): same-cache-line device atomicAdd from all block leaders
// serializes cross-XCD (~+45 us tail). Plain per-block store + trailing
// 1-block reduce wins. LESSON (R4): forcing waves/EU via __launch_bounds__
// 2nd arg spills to scratch; leave VGPR to the compiler.
// R8 theory: timed window = 2x 256MiB harness poison fills (~83us, immovable)
// + our kernels (~29us). Kernel memory floor = 83.9MB/6.3TBps = 13.3us;
// VALU floor ~9.5us (10 transcendentals/elem) -> target ~16us. Attack the
// 8+2 block tail (256-thread blocks) and per-element halo-load overhead.

__device__ __forceinline__ void load_row(float r[WIDTH + 2], const float* __restrict__ base,
                                         int t, int q) {
    // base -> tgt[b][0][d0]; r[0]=d0-1, r[1..8]=d0..d0+7, r[9]=d0+8
    if ((unsigned)t < TLEN) {
        const float* p = base + (size_t)t * DIM;
        const float4 a = *(const float4*)p;
        const float4 c = *(const float4*)(p + 4);
        r[0] = (q > 0)      ? p[-1] : 0.f;
        r[1] = a.x; r[2] = a.y; r[3] = a.z; r[4] = a.w;
        r[5] = c.x; r[6] = c.y; r[7] = c.z; r[8] = c.w;
        r[9] = (q < DG - 1) ? p[8]  : 0.f;
    } else {
#pragma unroll
        for (int i = 0; i < WIDTH + 2; ++i) r[i] = 0.f;
    }
}

__device__ __forceinline__ float elem_loss(float x, const float* rm, const float* r0,
                                           const float* rp, int e) {
    float v[9];
#pragma unroll
    for (int i = 0; i < 3; ++i) {
        v[0 + i] = fabsf(x - rm[e + i]);
        v[3 + i] = fabsf(x - r0[e + i]);
        v[6 + i] = fabsf(x - rp[e + i]);
    }
    const float center = v[4];
    // min3-shaped tree: 4x v_min3_f32 instead of a 9-op fmin chain
    const float m0 = fminf(fminf(v[0], v[1]), v[2]);
    const float m1 = fminf(fminf(v[3], v[4]), v[5]);
    const float m2 = fminf(fminf(v[6], v[7]), v[8]);
    const float m  = fminf(fminf(m0, m1), m2);
    const float cm = SMIN_C * m;
    float ex[9];
#pragma unroll
    for (int s = 0; s < 9; ++s)
        ex[s] = __builtin_amdgcn_exp2f(fmaf(-SMIN_C, v[s], cm));   // args <= 0; S in [1,9]
    const float S = ((ex[0] + ex[1]) + (ex[2] + ex[3]))
                  + (((ex[4] + ex[5]) + (ex[6] + ex[7])) + ex[8]); // pairwise: ILP
    return center + m - __builtin_amdgcn_logf(S) * SMIN_RC;        // logf builtin = log2
}

__global__ __launch_bounds__(THREADS) void jitter_kernel(
    const float* __restrict__ inp, const float* __restrict__ tgt,
    float* __restrict__ ws)
{
    __shared__ float wsum[THREADS / 64];

    const int n   = blockIdx.x * THREADS + threadIdx.x;
    const int q   = n % DG;
    const int rem = n / DG;
    const int tc  = rem % TCHUNKS;
    const int b   = rem / TCHUNKS;
    const int t0  = tc * TT;
    const int d0  = q * WIDTH;

    const float* tgb = tgt + (size_t)b * TLEN * DIM + d0;
    const float* inb = inp + (size_t)b * TLEN * DIM + d0;

    float rm[WIDTH + 2], r0[WIDTH + 2], rp[WIDTH + 2];
    load_row(rm, tgb, t0 - 1, q);
    load_row(r0, tgb, t0,     q);

    float acc = 0.f;
#pragma unroll
    for (int lt = 0; lt < TT; ++lt) {
        load_row(rp, tgb, t0 + lt + 1, q);
        const float* ip = inb + (size_t)(t0 + lt) * DIM;
        const float4 a = *(const float4*)ip;
        const float4 c = *(const float4*)(ip + 4);
        acc += elem_loss(a.x, rm, r0, rp, 0);
        acc += elem_loss(a.y, rm, r0, rp, 1);
        acc += elem_loss(a.z, rm, r0, rp, 2);
        acc += elem_loss(a.w, rm, r0, rp, 3);
        acc += elem_loss(c.x, rm, r0, rp, 4);
        acc += elem_loss(c.y, rm, r0, rp, 5);
        acc += elem_loss(c.z, rm, r0, rp, 6);
        acc += elem_loss(c.w, rm, r0, rp, 7);
#pragma unroll
        for (int i = 0; i < WIDTH + 2; ++i) { rm[i] = r0[i]; r0[i] = rp[i]; }
    }

    // block reduction -> one plain store per block (no atomics, no contention)
#pragma unroll
    for (int off = 32; off > 0; off >>= 1)
        acc += __shfl_down(acc, off, 64);
    const int lane = threadIdx.x & 63, wid = threadIdx.x >> 6;
    if (lane == 0) wsum[wid] = acc;
    __syncthreads();
    if (threadIdx.x == 0) {
        float tot = 0.f;
#pragma unroll
        for (int w = 0; w < THREADS / 64; ++w) tot += wsum[w];
        ws[blockIdx.x] = tot;
    }
}

__global__ __launch_bounds__(256) void reduce_kernel(const float* __restrict__ ws,
                                                     float* __restrict__ out) {
    __shared__ float wsum[4];
    float s = 0.f;
    for (int i = threadIdx.x; i < NBLOCKS; i += 256) s += ws[i];
#pragma unroll
    for (int off = 32; off > 0; off >>= 1)
        s += __shfl_down(s, off, 64);
    const int lane = threadIdx.x & 63, wid = threadIdx.x >> 6;
    if (lane == 0) wsum[wid] = s;
    __syncthreads();
    if (threadIdx.x == 0) {
        float tot = wsum[0] + wsum[1] + wsum[2] + wsum[3];
        out[0] = tot * (0.5f / (float)((size_t)BATCH * TLEN * DIM));
    }
}

extern "C" void kernel_launch(void* const* d_in, const int* in_sizes, int n_in,
                              void* d_out, int out_size, void* d_ws, size_t ws_size,
                              hipStream_t stream) {
    const float* inp = (const float*)d_in[0];
    const float* tgt = (const float*)d_in[1];
    float* ws  = (float*)d_ws;
    float* out = (float*)d_out;

    jitter_kernel<<<NBLOCKS, THREADS, 0, stream>>>(inp, tgt, ws);
    reduce_kernel<<<1, 256, 0, stream>>>(ws, out);
}